// Round 3
// baseline (25.330 us; speedup 1.0000x reference)
//
#include <hip/hip_runtime.h>

namespace fk {

struct V3 { float x, y, z; };
struct M3 { V3 c0, c1, c2; };   // column-major 3x3

__device__ __forceinline__ V3 axpy(float a, V3 x, V3 y) {
    return V3{ fmaf(a, x.x, y.x), fmaf(a, x.y, y.y), fmaf(a, x.z, y.z) };
}
__device__ __forceinline__ V3 sc(float a, V3 x) { return V3{ a * x.x, a * x.y, a * x.z }; }

// R * Rx(theta): col1' = c*c1 + s*c2 ; col2' = -s*c1 + c*c2
__device__ __forceinline__ M3 mulRx(const M3& R, float s, float c) {
    return M3{ R.c0,
               axpy(s,  R.c2, sc(c, R.c1)),
               axpy(-s, R.c1, sc(c, R.c2)) };
}
// R * Ry(theta): col0' = c*c0 - s*c2 ; col2' = s*c0 + c*c2
__device__ __forceinline__ M3 mulRy(const M3& R, float s, float c) {
    return M3{ axpy(-s, R.c2, sc(c, R.c0)),
               R.c1,
               axpy(s,  R.c0, sc(c, R.c2)) };
}

// One wave (64 threads) per block; each thread = one batch element.
// Outputs staged in LDS and flushed as the wave's contiguous 22272 B slab.
__global__ __launch_bounds__(64) void fk_kernel(const float* __restrict__ angles,
                                                float* __restrict__ out, int B) {
    __shared__ float lds[64 * 87];   // 22272 B -> 7 blocks/CU (LDS-capacity bound)

    const int tid = threadIdx.x;                 // lane in wave
    const int b = blockIdx.x * 64 + tid;         // batch element
    const bool valid = (b < B);

    if (valid) {
        // ---- load 24 angles: 6 x float4 ----
        const float4* ap = reinterpret_cast<const float4*>(angles + (size_t)b * 24);
        float q[24];
        {
            float4 v;
            v = ap[0]; q[0]=v.x;  q[1]=v.y;  q[2]=v.z;  q[3]=v.w;
            v = ap[1]; q[4]=v.x;  q[5]=v.y;  q[6]=v.z;  q[7]=v.w;
            v = ap[2]; q[8]=v.x;  q[9]=v.y;  q[10]=v.z; q[11]=v.w;
            v = ap[3]; q[12]=v.x; q[13]=v.y; q[14]=v.z; q[15]=v.w;
            v = ap[4]; q[16]=v.x; q[17]=v.y; q[18]=v.z; q[19]=v.w;
            v = ap[5]; q[20]=v.x; q[21]=v.y; q[22]=v.z; q[23]=v.w;
        }

        constexpr float MN[24] = {-0.523599f,-0.698132f,-0.349066f,0.f,0.f,0.f,-0.349066f,0.f,0.f,0.f,
                                  -0.349066f,0.f,0.f,0.f,0.f,-0.349066f,0.f,0.f,0.f,
                                  -1.0472f,0.f,-0.20944f,-0.698132f,0.f};
        constexpr float MX[24] = {0.174533f,0.488692f,0.349066f,1.5708f,1.5708f,1.5708f,0.349066f,1.5708f,1.5708f,1.5708f,
                                  0.349066f,1.5708f,1.5708f,1.5708f,0.785398f,0.349066f,1.5708f,1.5708f,1.5708f,
                                  1.0472f,1.22173f,0.20944f,0.698132f,1.5708f};
        float s[24], c[24];
        #pragma unroll
        for (int j = 0; j < 24; ++j) {
            float a = fminf(fmaxf(q[j], MN[j]), MX[j]);
            __sincosf(a, &s[j], &c[j]);
        }

        float* o = lds + tid * 87;   // stride 87 (odd) -> 2-way bank alias = free
        auto emit = [&](int node, V3 t) {
            o[node*3+0] = t.x; o[node*3+1] = t.y; o[node*3+2] = t.z;
        };

        // node 0: Ry(q0), t = 0
        M3 R0{ V3{c[0],0.f,-s[0]}, V3{0.f,1.f,0.f}, V3{s[0],0.f,c[0]} };
        emit(0, V3{0.f,0.f,0.f});
        // node 1: R1 = R0*Rx(q1), t1 = R0 @ (0,0,0.034)
        M3 R1 = mulRx(R0, s[1], c[1]);
        V3 t1 = sc(0.034f, R0.c2);
        emit(1, t1);

        // generic 5-node finger off node 1: base Ry at (bx,0,bz), 3x Rx links, fixed tip
        auto finger = [&](int n0, float sy, float cy,
                          float s1, float c1, float s2, float c2, float s3, float c3,
                          float bx, float bz) {
            M3 Ra = mulRy(R1, sy, cy);
            V3 ta = axpy(bx, R1.c0, axpy(bz, R1.c2, t1));
            emit(n0, ta);                                  // knuckle
            M3 Rb = mulRx(Ra, s1, c1);
            emit(n0+1, ta);                                // proximal base (zero trans)
            V3 tc = axpy(0.045f, Rb.c2, ta);
            M3 Rc = mulRx(Rb, s2, c2);
            emit(n0+2, tc);
            V3 td = axpy(0.025f, Rc.c2, tc);
            M3 Rd = mulRx(Rc, s3, c3);
            emit(n0+3, td);
            emit(n0+4, axpy(0.026f, Rd.c2, td));           // fingertip (fixed)
        };
        finger(2,   s[2],  c[2],  s[3],c[3],   s[4],c[4],   s[5],c[5],  -0.033f, 0.095f);
        finger(7,   s[6],  c[6],  s[7],c[7],   s[8],c[8],   s[9],c[9],  -0.011f, 0.099f);
        finger(12, -s[10], c[10], s[11],c[11], s[12],c[12], s[13],c[13], 0.011f, 0.095f); // axis (0,-1,0)

        // little finger: extra metacarpal joint about axis u=(ux,0,uz) (Rodrigues)
        {
            const float ux = 0.573576f, uz = -0.819152f;
            float omc = 1.f - c[14];
            float l00 = fmaf(omc * ux, ux, c[14]);
            float l10 = s[14] * uz;
            float l20 = omc * ux * uz;
            float l01 = -s[14] * uz;
            float l21 = s[14] * ux;
            float l02 = omc * ux * uz;
            float l12 = -s[14] * ux;
            float l22 = fmaf(omc * uz, uz, c[14]);
            M3 R17;
            R17.c0 = axpy(l20, R1.c2, axpy(l10,  R1.c1, sc(l00, R1.c0)));
            R17.c1 = axpy(l21, R1.c2, axpy(c[14],R1.c1, sc(l01, R1.c0)));
            R17.c2 = axpy(l22, R1.c2, axpy(l12,  R1.c1, sc(l02, R1.c0)));
            V3 t17 = axpy(0.033f, R1.c0, axpy(0.02071f, R1.c2, t1));
            emit(17, t17);
            V3 t18 = axpy(0.06579f, R17.c2, t17);
            M3 R18 = mulRy(R17, -s[15], c[15]);            // axis (0,-1,0)
            emit(18, t18);
            M3 R19 = mulRx(R18, s[16], c[16]);
            emit(19, t18);                                 // zero trans
            V3 t20 = axpy(0.045f, R19.c2, t18);
            M3 R20 = mulRx(R19, s[17], c[17]);
            emit(20, t20);
            V3 t21 = axpy(0.025f, R20.c2, t20);
            M3 R21 = mulRx(R20, s[18], c[18]);
            emit(21, t21);
            emit(22, axpy(0.026f, R21.c2, t21));
        }

        // thumb: node23 has fixed base quat Qb, node27 has fixed quat Qd
        {
            const float k = 0.70710678f;
            float m00 = -k * c[19], m10 = -s[19];
            float m01 =  k * s[19], m11 = -c[19];
            M3 R23;
            R23.c0 = axpy(m00, R1.c2, axpy(m10, R1.c1, sc(m00, R1.c0)));
            R23.c1 = axpy(m01, R1.c2, axpy(m11, R1.c1, sc(m01, R1.c0)));
            R23.c2 = axpy(k, R1.c2, sc(-k, R1.c0));
            V3 t23 = axpy(-0.034f, R1.c0, axpy(-0.0085f, R1.c1, axpy(0.029f, R1.c2, t1)));
            emit(23, t23);
            M3 R24 = mulRx(R23, -s[20], c[20]);            // axis (-1,0,0)
            emit(24, t23);                                 // zero trans
            V3 t25 = axpy(0.038f, R24.c2, t23);
            M3 R25 = mulRx(R24, s[21], c[21]);
            emit(25, t25);
            M3 R26 = mulRy(R25, -s[22], c[22]);            // axis (0,-1,0)
            emit(26, t25);                                 // zero trans
            V3 t27 = axpy(0.032f, R26.c2, t25);
            // Rl27 = Qd @ Rx(q23), columns: (0,-1,0), (c,0,s), (-s,0,c)
            M3 R27;
            R27.c0 = sc(-1.f, R26.c1);
            R27.c1 = axpy(s[23],  R26.c2, sc(c[23], R26.c0));
            R27.c2 = axpy(-s[23], R26.c0, sc(c[23], R26.c2));
            emit(27, t27);
            emit(28, axpy(0.0275f, R27.c2, t27));
        }
    }

    __syncthreads();   // single wave: near-free; orders LDS writes before flush reads

    // ---- coalesced flush, BATCHED: issue 11 ds_read_b128, one wait, 11 stores ----
    // (dependent read->store pairs were ~22x ~130cyc of serialized LDS latency)
    const size_t base_f = (size_t)blockIdx.x * 64 * 87;   // float index of slab start
    if ((size_t)(blockIdx.x + 1) * 64 <= (size_t)B) {
        const float4* lsrc = reinterpret_cast<const float4*>(lds);
        float4* gdst = reinterpret_cast<float4*>(out + base_f);
        // slab = 1392 float4s; 21 full 64-lane iters + 48-lane tail
        {
            float4 v[11];
            #pragma unroll
            for (int m = 0; m < 11; ++m) v[m] = lsrc[m * 64 + tid];
            #pragma unroll
            for (int m = 0; m < 11; ++m) gdst[m * 64 + tid] = v[m];
        }
        {
            float4 v[11];
            #pragma unroll
            for (int m = 11; m < 21; ++m) v[m - 11] = lsrc[m * 64 + tid];
            const bool tail = (21 * 64 + tid) < 1392;
            if (tail) v[10] = lsrc[21 * 64 + tid];
            #pragma unroll
            for (int m = 11; m < 21; ++m) gdst[m * 64 + tid] = v[m - 11];
            if (tail) gdst[21 * 64 + tid] = v[10];
        }
    } else {
        // tail wave: scalar guarded stores
        const size_t limit = (size_t)B * 87;
        for (int m = 0; m < 87; ++m) {
            size_t f = (size_t)m * 64 + tid;
            if (base_f + f < limit) out[base_f + f] = lds[f];
        }
    }
}

} // namespace fk

extern "C" void kernel_launch(void* const* d_in, const int* in_sizes, int n_in,
                              void* d_out, int out_size, void* d_ws, size_t ws_size,
                              hipStream_t stream) {
    const float* angles = (const float*)d_in[0];
    float* out = (float*)d_out;
    const int B = in_sizes[0] / 24;
    const int grid = (B + 63) / 64;
    fk::fk_kernel<<<grid, 64, 0, stream>>>(angles, out, B);
}

// Round 5
// 23.064 us; speedup vs baseline: 1.0982x; 1.0982x over previous
//
#include <hip/hip_runtime.h>

namespace fk {

typedef float f32x4 __attribute__((ext_vector_type(4)));

struct V3 { float x, y, z; };
struct M3 { V3 c0, c1, c2; };   // column-major 3x3

__device__ __forceinline__ V3 axpy(float a, V3 x, V3 y) {
    return V3{ fmaf(a, x.x, y.x), fmaf(a, x.y, y.y), fmaf(a, x.z, y.z) };
}
__device__ __forceinline__ V3 sc(float a, V3 x) { return V3{ a * x.x, a * x.y, a * x.z }; }

// R * Rx(theta): col1' = c*c1 + s*c2 ; col2' = -s*c1 + c*c2
__device__ __forceinline__ M3 mulRx(const M3& R, float s, float c) {
    return M3{ R.c0,
               axpy(s,  R.c2, sc(c, R.c1)),
               axpy(-s, R.c1, sc(c, R.c2)) };
}
// R * Ry(theta): col0' = c*c0 - s*c2 ; col2' = s*c0 + c*c2
__device__ __forceinline__ M3 mulRy(const M3& R, float s, float c) {
    return M3{ axpy(-s, R.c2, sc(c, R.c0)),
               R.c1,
               axpy(s,  R.c0, sc(c, R.c2)) };
}

// One wave (64 threads) per block; each thread = one batch element.
// Outputs staged in LDS and flushed as the wave's contiguous 22272 B slab.
// Flush uses nontemporal stores: 91 MB write-once should bypass L2 allocation.
__global__ __launch_bounds__(64) void fk_kernel(const float* __restrict__ angles,
                                                float* __restrict__ out, int B) {
    __shared__ float lds[64 * 87];   // 22272 B -> 7 blocks/CU (LDS-capacity bound)

    const int tid = threadIdx.x;                 // lane in wave
    const int b = blockIdx.x * 64 + tid;         // batch element
    const bool valid = (b < B);

    if (valid) {
        // ---- load 24 angles: 6 x float4 ----
        const float4* ap = reinterpret_cast<const float4*>(angles + (size_t)b * 24);
        float q[24];
        {
            float4 v;
            v = ap[0]; q[0]=v.x;  q[1]=v.y;  q[2]=v.z;  q[3]=v.w;
            v = ap[1]; q[4]=v.x;  q[5]=v.y;  q[6]=v.z;  q[7]=v.w;
            v = ap[2]; q[8]=v.x;  q[9]=v.y;  q[10]=v.z; q[11]=v.w;
            v = ap[3]; q[12]=v.x; q[13]=v.y; q[14]=v.z; q[15]=v.w;
            v = ap[4]; q[16]=v.x; q[17]=v.y; q[18]=v.z; q[19]=v.w;
            v = ap[5]; q[20]=v.x; q[21]=v.y; q[22]=v.z; q[23]=v.w;
        }

        constexpr float MN[24] = {-0.523599f,-0.698132f,-0.349066f,0.f,0.f,0.f,-0.349066f,0.f,0.f,0.f,
                                  -0.349066f,0.f,0.f,0.f,0.f,-0.349066f,0.f,0.f,0.f,
                                  -1.0472f,0.f,-0.20944f,-0.698132f,0.f};
        constexpr float MX[24] = {0.174533f,0.488692f,0.349066f,1.5708f,1.5708f,1.5708f,0.349066f,1.5708f,1.5708f,1.5708f,
                                  0.349066f,1.5708f,1.5708f,1.5708f,0.785398f,0.349066f,1.5708f,1.5708f,1.5708f,
                                  1.0472f,1.22173f,0.20944f,0.698132f,1.5708f};
        float s[24], c[24];
        #pragma unroll
        for (int j = 0; j < 24; ++j) {
            float a = fminf(fmaxf(q[j], MN[j]), MX[j]);
            __sincosf(a, &s[j], &c[j]);
        }

        float* o = lds + tid * 87;   // stride 87 (odd) -> 2-way bank alias = free
        auto emit = [&](int node, V3 t) {
            o[node*3+0] = t.x; o[node*3+1] = t.y; o[node*3+2] = t.z;
        };

        // node 0: Ry(q0), t = 0
        M3 R0{ V3{c[0],0.f,-s[0]}, V3{0.f,1.f,0.f}, V3{s[0],0.f,c[0]} };
        emit(0, V3{0.f,0.f,0.f});
        // node 1: R1 = R0*Rx(q1), t1 = R0 @ (0,0,0.034)
        M3 R1 = mulRx(R0, s[1], c[1]);
        V3 t1 = sc(0.034f, R0.c2);
        emit(1, t1);

        // generic 5-node finger off node 1: base Ry at (bx,0,bz), 3x Rx links, fixed tip
        auto finger = [&](int n0, float sy, float cy,
                          float s1, float c1, float s2, float c2, float s3, float c3,
                          float bx, float bz) {
            M3 Ra = mulRy(R1, sy, cy);
            V3 ta = axpy(bx, R1.c0, axpy(bz, R1.c2, t1));
            emit(n0, ta);                                  // knuckle
            M3 Rb = mulRx(Ra, s1, c1);
            emit(n0+1, ta);                                // proximal base (zero trans)
            V3 tc = axpy(0.045f, Rb.c2, ta);
            M3 Rc = mulRx(Rb, s2, c2);
            emit(n0+2, tc);
            V3 td = axpy(0.025f, Rc.c2, tc);
            M3 Rd = mulRx(Rc, s3, c3);
            emit(n0+3, td);
            emit(n0+4, axpy(0.026f, Rd.c2, td));           // fingertip (fixed)
        };
        finger(2,   s[2],  c[2],  s[3],c[3],   s[4],c[4],   s[5],c[5],  -0.033f, 0.095f);
        finger(7,   s[6],  c[6],  s[7],c[7],   s[8],c[8],   s[9],c[9],  -0.011f, 0.099f);
        finger(12, -s[10], c[10], s[11],c[11], s[12],c[12], s[13],c[13], 0.011f, 0.095f); // axis (0,-1,0)

        // little finger: extra metacarpal joint about axis u=(ux,0,uz) (Rodrigues)
        {
            const float ux = 0.573576f, uz = -0.819152f;
            float omc = 1.f - c[14];
            float l00 = fmaf(omc * ux, ux, c[14]);
            float l10 = s[14] * uz;
            float l20 = omc * ux * uz;
            float l01 = -s[14] * uz;
            float l21 = s[14] * ux;
            float l02 = omc * ux * uz;
            float l12 = -s[14] * ux;
            float l22 = fmaf(omc * uz, uz, c[14]);
            M3 R17;
            R17.c0 = axpy(l20, R1.c2, axpy(l10,  R1.c1, sc(l00, R1.c0)));
            R17.c1 = axpy(l21, R1.c2, axpy(c[14],R1.c1, sc(l01, R1.c0)));
            R17.c2 = axpy(l22, R1.c2, axpy(l12,  R1.c1, sc(l02, R1.c0)));
            V3 t17 = axpy(0.033f, R1.c0, axpy(0.02071f, R1.c2, t1));
            emit(17, t17);
            V3 t18 = axpy(0.06579f, R17.c2, t17);
            M3 R18 = mulRy(R17, -s[15], c[15]);            // axis (0,-1,0)
            emit(18, t18);
            M3 R19 = mulRx(R18, s[16], c[16]);
            emit(19, t18);                                 // zero trans
            V3 t20 = axpy(0.045f, R19.c2, t18);
            M3 R20 = mulRx(R19, s[17], c[17]);
            emit(20, t20);
            V3 t21 = axpy(0.025f, R20.c2, t20);
            M3 R21 = mulRx(R20, s[18], c[18]);
            emit(21, t21);
            emit(22, axpy(0.026f, R21.c2, t21));
        }

        // thumb: node23 has fixed base quat Qb, node27 has fixed quat Qd
        {
            const float k = 0.70710678f;
            float m00 = -k * c[19], m10 = -s[19];
            float m01 =  k * s[19], m11 = -c[19];
            M3 R23;
            R23.c0 = axpy(m00, R1.c2, axpy(m10, R1.c1, sc(m00, R1.c0)));
            R23.c1 = axpy(m01, R1.c2, axpy(m11, R1.c1, sc(m01, R1.c0)));
            R23.c2 = axpy(k, R1.c2, sc(-k, R1.c0));
            V3 t23 = axpy(-0.034f, R1.c0, axpy(-0.0085f, R1.c1, axpy(0.029f, R1.c2, t1)));
            emit(23, t23);
            M3 R24 = mulRx(R23, -s[20], c[20]);            // axis (-1,0,0)
            emit(24, t23);                                 // zero trans
            V3 t25 = axpy(0.038f, R24.c2, t23);
            M3 R25 = mulRx(R24, s[21], c[21]);
            emit(25, t25);
            M3 R26 = mulRy(R25, -s[22], c[22]);            // axis (0,-1,0)
            emit(26, t25);                                 // zero trans
            V3 t27 = axpy(0.032f, R26.c2, t25);
            // Rl27 = Qd @ Rx(q23), columns: (0,-1,0), (c,0,s), (-s,0,c)
            M3 R27;
            R27.c0 = sc(-1.f, R26.c1);
            R27.c1 = axpy(s[23],  R26.c2, sc(c[23], R26.c0));
            R27.c2 = axpy(-s[23], R26.c0, sc(c[23], R26.c2));
            emit(27, t27);
            emit(28, axpy(0.0275f, R27.c2, t27));
        }
    }

    __syncthreads();   // single wave: near-free; orders LDS writes before flush reads

    // ---- coalesced flush (simple R2 loop) with NONTEMPORAL stores ----
    // f32x4 (clang ext_vector_type) is accepted by __builtin_nontemporal_store;
    // HIP_vector_type float4 is not.
    const size_t base_f = (size_t)blockIdx.x * 64 * 87;   // float index of slab start
    if ((size_t)(blockIdx.x + 1) * 64 <= (size_t)B) {
        // full wave: 1392 float4s, 16B-aligned both sides (22272 % 16 == 0)
        const f32x4* lsrc = reinterpret_cast<const f32x4*>(lds);
        f32x4* gdst = reinterpret_cast<f32x4*>(out + base_f);
        #pragma unroll
        for (int m = 0; m < 21; ++m)
            __builtin_nontemporal_store(lsrc[m * 64 + tid], &gdst[m * 64 + tid]);
        int g = 21 * 64 + tid;
        if (g < 1392) __builtin_nontemporal_store(lsrc[g], &gdst[g]);
    } else {
        // tail wave: scalar guarded stores
        const size_t limit = (size_t)B * 87;
        for (int m = 0; m < 87; ++m) {
            size_t f = (size_t)m * 64 + tid;
            if (base_f + f < limit) __builtin_nontemporal_store(lds[f], &out[base_f + f]);
        }
    }
}

} // namespace fk

extern "C" void kernel_launch(void* const* d_in, const int* in_sizes, int n_in,
                              void* d_out, int out_size, void* d_ws, size_t ws_size,
                              hipStream_t stream) {
    const float* angles = (const float*)d_in[0];
    float* out = (float*)d_out;
    const int B = in_sizes[0] / 24;
    const int grid = (B + 63) / 64;
    fk::fk_kernel<<<grid, 64, 0, stream>>>(angles, out, B);
}